// Round 7
// baseline (208.757 us; speedup 1.0000x reference)
//
#include <hip/hip_runtime.h>
#include <hip/hip_bf16.h>

#define N_NODES 8192
#define N_EDGES 262144
#define F_INDIM 128
#define HID 256
#define F_OUT 128
#define N_GRAPHS 64
#define WPR (N_NODES / 32)   // 256 words per bitmask row
#define CAP 160              // max supported degree (Poisson(64), 12 sigma headroom)

struct alignas(8) bf4 { __hip_bfloat16 a, b, c, d; };

__device__ inline float2 bf2unpack(unsigned int u) {
    float2 r;
    r.x = __uint_as_float(u << 16);          // low ushort  -> col 2l
    r.y = __uint_as_float(u & 0xffff0000u);  // high ushort -> col 2l+1
    return r;
}

// ---------------------------------------------------------------------------
// 0. Cast X (f32) -> Xh (bf16), float4 vectorized
// ---------------------------------------------------------------------------
__global__ __launch_bounds__(256) void cast_x(const float* __restrict__ X,
                                              __hip_bfloat16* __restrict__ Xh) {
    int i = blockIdx.x * 256 + threadIdx.x;   // i < N*F/4
    float4 v = ((const float4*)X)[i];
    bf4 o;
    o.a = __float2bfloat16(v.x); o.b = __float2bfloat16(v.y);
    o.c = __float2bfloat16(v.z); o.d = __float2bfloat16(v.w);
    ((bf4*)Xh)[i] = o;
}

// ---------------------------------------------------------------------------
// 1. Edge scatter into symmetric bitmask (dedup by construction)  [R2 proven]
// ---------------------------------------------------------------------------
__global__ __launch_bounds__(256) void scatter_edges(const int* __restrict__ ei,
                                                     unsigned int* __restrict__ mask) {
    int e = blockIdx.x * blockDim.x + threadIdx.x;
    if (e >= N_EDGES) return;
    int s = ei[e];
    int d = ei[N_EDGES + e];
    if ((unsigned)s >= N_NODES || (unsigned)d >= N_NODES) return;  // safety guard
    atomicOr(&mask[(size_t)s * WPR + (d >> 5)], 1u << (d & 31));
    atomicOr(&mask[(size_t)d * WPR + (s >> 5)], 1u << (s & 31));
}

// ---------------------------------------------------------------------------
// 2. Bitmask -> fixed-stride adjacency + deg + dis. One wave/row. [R2 proven]
// ---------------------------------------------------------------------------
__global__ __launch_bounds__(256) void build_adj(const unsigned int* __restrict__ mask,
                                                 int* __restrict__ adj,
                                                 int* __restrict__ deg,
                                                 float* __restrict__ dis) {
    int row = (blockIdx.x * blockDim.x + threadIdx.x) >> 6;
    int lane = threadIdx.x & 63;
    if (row >= N_NODES) return;
    const uint4* r = (const uint4*)(mask + (size_t)row * WPR);
    uint4 v = r[lane];
    int cnt = __popc(v.x) + __popc(v.y) + __popc(v.z) + __popc(v.w);
    int scan = cnt;  // inclusive scan across 64 lanes
    for (int off = 1; off < 64; off <<= 1) {
        int n = __shfl_up(scan, off);
        if (lane >= off) scan += n;
    }
    int tot = __shfl(scan, 63);
    int idx = scan - cnt;  // exclusive prefix = my write base
    int* ap = adj + (size_t)row * CAP;
    int wbase = lane << 7;  // lane*4 words * 32 bits
    unsigned int wd;
    wd = v.x; while (wd) { int b = __ffs(wd) - 1; wd &= wd - 1; if (idx < CAP) ap[idx] = wbase + b;      ++idx; }
    wd = v.y; while (wd) { int b = __ffs(wd) - 1; wd &= wd - 1; if (idx < CAP) ap[idx] = wbase + 32 + b; ++idx; }
    wd = v.z; while (wd) { int b = __ffs(wd) - 1; wd &= wd - 1; if (idx < CAP) ap[idx] = wbase + 64 + b; ++idx; }
    wd = v.w; while (wd) { int b = __ffs(wd) - 1; wd &= wd - 1; if (idx < CAP) ap[idx] = wbase + 96 + b; ++idx; }
    if (lane == 63) { deg[row] = tot; dis[row] = rsqrtf((float)(tot + 1)); }  // +1: identity
}

// ---------------------------------------------------------------------------
// 3. build_u: u[g][j] = sum_{i in N(j), batch[i]==g} dis_i + [batch_j==g]*dis_j
//    One wave per node j; 64 lanes = 64 graphs; LDS atomics for the histogram.
// ---------------------------------------------------------------------------
__global__ __launch_bounds__(256) void build_u(const int* __restrict__ adj,
                                               const int* __restrict__ deg,
                                               const float* __restrict__ dis,
                                               const int* __restrict__ batch,
                                               float* __restrict__ u) {
    int w = threadIdx.x >> 6, lane = threadIdx.x & 63;
    int j = blockIdx.x * 4 + w;
    __shared__ float ul[4][64];
    ul[w][lane] = 0.0f;
    __syncthreads();
    int d = deg[j]; if (d > CAP) d = CAP;
    for (int t = lane; t < d; t += 64) {
        int i = adj[(size_t)j * CAP + t];
        atomicAdd(&ul[w][batch[i] & 63], dis[i]);
    }
    if (lane == 0) atomicAdd(&ul[w][batch[j] & 63], dis[j]);  // +I diagonal
    __syncthreads();
    u[(size_t)lane * N_NODES + j] = ul[w][lane];
}

// ---------------------------------------------------------------------------
// 4. spmm_x: wave-per-row, uint (2xbf16) vectorized gather, fused sv.
//    G[i][c] = dis_i*(dis_i*X[i][c] + sum_j dis_j*X[j][c]);  sv = (A_hat@1)
// ---------------------------------------------------------------------------
__global__ __launch_bounds__(256) void spmm_x(const int* __restrict__ adj,
                                              const int* __restrict__ deg,
                                              const __hip_bfloat16* __restrict__ Xh,
                                              const float* __restrict__ dis,
                                              float* __restrict__ G,
                                              float* __restrict__ sv) {
    int w = threadIdx.x >> 6, lane = threadIdx.x & 63;
    int i = blockIdx.x * 4 + w;
    __shared__ int nb[4][CAP];
    __shared__ float nbd[4][CAP];
    int d = deg[i]; if (d > CAP) d = CAP;
    const unsigned int* Xu = (const unsigned int*)Xh;  // row stride 64 uints
    float p = 0.0f;
    for (int t = lane; t < d; t += 64) {
        int j = adj[(size_t)i * CAP + t];
        float dj = dis[j];
        nb[w][t] = j; nbd[w][t] = dj;
        p += dj;
    }
    __syncthreads();
    for (int off = 32; off; off >>= 1) p += __shfl_down(p, off);
    float di = dis[i];
    if (lane == 0) sv[i] = di * (di + p);
    float2 xi = bf2unpack(Xu[(size_t)i * 64 + lane]);
    float2 a0 = {di * xi.x, di * xi.y};
    float2 a1 = {0,0}, a2 = {0,0}, a3 = {0,0}, a4 = {0,0}, a5 = {0,0}, a6 = {0,0}, a7 = {0,0};
    int k = 0;
    for (; k + 8 <= d; k += 8) {
#define GATH(Q, ACC) { int j = nb[w][k+Q]; float dj = nbd[w][k+Q]; \
        float2 f = bf2unpack(Xu[(size_t)j * 64 + lane]); \
        ACC.x += dj * f.x; ACC.y += dj * f.y; }
        GATH(0, a0) GATH(1, a1) GATH(2, a2) GATH(3, a3)
        GATH(4, a4) GATH(5, a5) GATH(6, a6) GATH(7, a7)
    }
    for (; k < d; ++k) GATH(0, a0)
#undef GATH
    float2 s;
    s.x = ((a0.x + a1.x) + (a2.x + a3.x)) + ((a4.x + a5.x) + (a6.x + a7.x));
    s.y = ((a0.y + a1.y) + (a2.y + a3.y)) + ((a4.y + a5.y) + (a6.y + a7.y));
    float2 o = {di * s.x, di * s.y};
    ((float2*)(G + (size_t)i * F_INDIM))[lane] = o;
}

// ---------------------------------------------------------------------------
// 5. GEMM1 register-tiled: H = relu(G@W1 + sv*b1).
//    Block = 16 rows x 256 cols; thread = 4 rows x 4 cols.
// ---------------------------------------------------------------------------
__global__ __launch_bounds__(256) void gemm1_v5(const float* __restrict__ G,
                                                const float* __restrict__ W1,
                                                const float* __restrict__ b1,
                                                const float* __restrict__ sv,
                                                float* __restrict__ H) {
    int i0 = blockIdx.x * 16;
    int t = threadIdx.x;
    int tc = t & 63;   // cols 4*tc..4*tc+3
    int tr = t >> 6;   // rows 4*tr..4*tr+3
    __shared__ float xs[16][F_INDIM];   // 8 KB
    for (int v = t; v < 16 * F_INDIM / 4; v += 256) {
        int r = v >> 5, c4 = (v & 31) << 2;
        *(float4*)&xs[r][c4] = *(const float4*)&G[(size_t)(i0 + r) * F_INDIM + c4];
    }
    __syncthreads();
    float4 acc0 = {0,0,0,0}, acc1 = {0,0,0,0}, acc2 = {0,0,0,0}, acc3 = {0,0,0,0};
    const float* wp = W1 + 4 * tc;
    for (int k = 0; k < F_INDIM; k += 4) {
        float4 w0 = *(const float4*)&wp[(size_t)(k + 0) * HID];
        float4 w1 = *(const float4*)&wp[(size_t)(k + 1) * HID];
        float4 w2 = *(const float4*)&wp[(size_t)(k + 2) * HID];
        float4 w3 = *(const float4*)&wp[(size_t)(k + 3) * HID];
#define ROW(R, ACC) { \
        float4 g4 = *(const float4*)&xs[4 * tr + R][k]; \
        ACC.x += g4.x*w0.x; ACC.y += g4.x*w0.y; ACC.z += g4.x*w0.z; ACC.w += g4.x*w0.w; \
        ACC.x += g4.y*w1.x; ACC.y += g4.y*w1.y; ACC.z += g4.y*w1.z; ACC.w += g4.y*w1.w; \
        ACC.x += g4.z*w2.x; ACC.y += g4.z*w2.y; ACC.z += g4.z*w2.z; ACC.w += g4.z*w2.w; \
        ACC.x += g4.w*w3.x; ACC.y += g4.w*w3.y; ACC.z += g4.w*w3.z; ACC.w += g4.w*w3.w; }
        ROW(0, acc0) ROW(1, acc1) ROW(2, acc2) ROW(3, acc3)
#undef ROW
    }
    float4 b = *(const float4*)&b1[4 * tc];
#define EPI(R, ACC) { \
        int i = i0 + 4 * tr + R; float s = sv[i]; float4 res = ACC; \
        res.x = fmaxf(res.x + s * b.x, 0.f); res.y = fmaxf(res.y + s * b.y, 0.f); \
        res.z = fmaxf(res.z + s * b.z, 0.f); res.w = fmaxf(res.w + s * b.w, 0.f); \
        *(float4*)&H[(size_t)i * HID + 4 * tc] = res; }
    EPI(0, acc0) EPI(1, acc1) EPI(2, acc2) EPI(3, acc3)
#undef EPI
}

// ---------------------------------------------------------------------------
// 6. GEMM2 register-tiled: M2ph[i][t] = bf16(dis_i*(H[i,:]@W2 + b2)).
//    Block = 16 rows x 128 cols; thread = 2 rows x 4 cols.
// ---------------------------------------------------------------------------
__global__ __launch_bounds__(256) void gemm2_v5(const float* __restrict__ H,
                                                const float* __restrict__ W2,
                                                const float* __restrict__ b2,
                                                const float* __restrict__ dis,
                                                __hip_bfloat16* __restrict__ M2ph) {
    int i0 = blockIdx.x * 16;
    int t = threadIdx.x;
    int tc = t & 31;   // cols 4*tc..4*tc+3
    int tr = t >> 5;   // rows 2*tr, 2*tr+1
    __shared__ float hs[16][HID];   // 16 KB
    for (int v = t; v < 16 * HID / 4; v += 256) {
        int r = v >> 6, c4 = (v & 63) << 2;
        *(float4*)&hs[r][c4] = *(const float4*)&H[(size_t)(i0 + r) * HID + c4];
    }
    __syncthreads();
    float4 acc0 = {0,0,0,0}, acc1 = {0,0,0,0};
    const float* wp = W2 + 4 * tc;
    for (int k = 0; k < HID; k += 4) {
        float4 w0 = *(const float4*)&wp[(size_t)(k + 0) * F_OUT];
        float4 w1 = *(const float4*)&wp[(size_t)(k + 1) * F_OUT];
        float4 w2 = *(const float4*)&wp[(size_t)(k + 2) * F_OUT];
        float4 w3 = *(const float4*)&wp[(size_t)(k + 3) * F_OUT];
#define ROW(R, ACC) { \
        float4 g4 = *(const float4*)&hs[2 * tr + R][k]; \
        ACC.x += g4.x*w0.x; ACC.y += g4.x*w0.y; ACC.z += g4.x*w0.z; ACC.w += g4.x*w0.w; \
        ACC.x += g4.y*w1.x; ACC.y += g4.y*w1.y; ACC.z += g4.y*w1.z; ACC.w += g4.y*w1.w; \
        ACC.x += g4.z*w2.x; ACC.y += g4.z*w2.y; ACC.z += g4.z*w2.z; ACC.w += g4.z*w2.w; \
        ACC.x += g4.w*w3.x; ACC.y += g4.w*w3.y; ACC.z += g4.w*w3.z; ACC.w += g4.w*w3.w; }
        ROW(0, acc0) ROW(1, acc1)
#undef ROW
    }
    float4 b = *(const float4*)&b2[4 * tc];
#define EPI(R, ACC) { \
        int i = i0 + 2 * tr + R; float dd = dis[i]; float4 res = ACC; \
        bf4 o; o.a = __float2bfloat16(dd * (res.x + b.x)); o.b = __float2bfloat16(dd * (res.y + b.y)); \
        o.c = __float2bfloat16(dd * (res.z + b.z)); o.d = __float2bfloat16(dd * (res.w + b.w)); \
        *(bf4*)(M2ph + (size_t)i * F_OUT + 4 * tc) = o; }
    EPI(0, acc0) EPI(1, acc1)
#undef EPI
}

// ---------------------------------------------------------------------------
// 7. wpool_a: part[g][q][c] = sum_{j in quarter q} u[g][j] * M2ph[j][c]
// ---------------------------------------------------------------------------
__global__ __launch_bounds__(128) void wpool_a(const float* __restrict__ u,
                                               const __hip_bfloat16* __restrict__ M2ph,
                                               float* __restrict__ part) {
    int g = blockIdx.x, q = blockIdx.y, c = threadIdx.x;
    const unsigned short* Mu = (const unsigned short*)M2ph;
    __shared__ float us[256];
    float a0 = 0.f, a1 = 0.f, a2 = 0.f, a3 = 0.f, a4 = 0.f, a5 = 0.f, a6 = 0.f, a7 = 0.f;
    int jend = (q + 1) * (N_NODES / 4);
    for (int j0 = q * (N_NODES / 4); j0 < jend; j0 += 256) {
        __syncthreads();
        us[c]       = u[(size_t)g * N_NODES + j0 + c];
        us[c + 128] = u[(size_t)g * N_NODES + j0 + c + 128];
        __syncthreads();
        for (int jj = 0; jj < 256; jj += 8) {
#define TERM(Q, ACC) ACC += us[jj + Q] * __uint_as_float((unsigned)Mu[(size_t)(j0 + jj + Q) * F_OUT + c] << 16);
            TERM(0, a0) TERM(1, a1) TERM(2, a2) TERM(3, a3)
            TERM(4, a4) TERM(5, a5) TERM(6, a6) TERM(7, a7)
#undef TERM
        }
    }
    float s = ((a0 + a1) + (a2 + a3)) + ((a4 + a5) + (a6 + a7));
    part[((size_t)g * 4 + q) * F_OUT + c] = s;
}

// ---------------------------------------------------------------------------
// 8. wpool_b: out[g][c] = (sum_q part[g][q][c]) / cnt_g
// ---------------------------------------------------------------------------
__global__ __launch_bounds__(128) void wpool_b(const float* __restrict__ part,
                                               const int* __restrict__ batch,
                                               float* __restrict__ out) {
    int g = blockIdx.x, c = threadIdx.x;
    int lo = 0, hi = N_NODES;
    while (lo < hi) { int m = (lo + hi) >> 1; if (batch[m] < g) lo = m + 1; else hi = m; }
    int start = lo;
    hi = N_NODES;
    while (lo < hi) { int m = (lo + hi) >> 1; if (batch[m] < g + 1) lo = m + 1; else hi = m; }
    int cnt = lo - start;
    float s = part[((size_t)g * 4 + 0) * F_OUT + c] + part[((size_t)g * 4 + 1) * F_OUT + c]
            + part[((size_t)g * 4 + 2) * F_OUT + c] + part[((size_t)g * 4 + 3) * F_OUT + c];
    out[(size_t)g * F_OUT + c] = s / (float)(cnt > 0 ? cnt : 1);
}

// ---------------------------------------------------------------------------
extern "C" void kernel_launch(void* const* d_in, const int* in_sizes, int n_in,
                              void* d_out, int out_size, void* d_ws, size_t ws_size,
                              hipStream_t stream) {
    const float* X  = (const float*)d_in[0];
    const float* W1 = (const float*)d_in[1];
    const float* b1 = (const float*)d_in[2];
    const float* W2 = (const float*)d_in[3];
    const float* b2 = (const float*)d_in[4];
    const int* ei    = (const int*)d_in[5];
    const int* batch = (const int*)d_in[6];
    float* out = (float*)d_out;

    char* ws = (char*)d_ws;
    // [0, 8MB): mask during build; after build_adj it is dead and the region
    // is reused for u (2MB), M2ph (2MB), part (128KB).
    unsigned int* mask   = (unsigned int*)(ws);
    float* u             = (float*)(ws);                    // 2 MB (64x8192)
    __hip_bfloat16* M2ph = (__hip_bfloat16*)(ws + 2097152); // 2 MB (8192x128)
    float* part          = (float*)(ws + 4194304);          // 128 KB (64x4x128)
    float* G   = (float*)(ws + 8388608);                    // 4 MB (8192x128 f32)
    __hip_bfloat16* Xh = (__hip_bfloat16*)(ws + 12582912);  // 2 MB (8192x128 bf16)
    float* H   = (float*)(ws + 16777216);                   // 8 MB (8192x256 f32)
    int*   adj = (int*)(ws + 25165824);                     // 5.25 MB
    int*   deg = (int*)(ws + 30408704);                     // 32 KB
    float* dis = (float*)(ws + 30441472);                   // 32 KB
    float* sv  = (float*)(ws + 30474240);                   // 32 KB

    cast_x<<<(N_NODES * F_INDIM / 4) / 256, 256, 0, stream>>>(X, Xh);
    hipMemsetAsync(mask, 0, (size_t)N_NODES * WPR * sizeof(unsigned int), stream);
    scatter_edges<<<N_EDGES / 256, 256, 0, stream>>>(ei, mask);
    build_adj<<<N_NODES / 4, 256, 0, stream>>>(mask, adj, deg, dis);
    build_u<<<N_NODES / 4, 256, 0, stream>>>(adj, deg, dis, batch, u);
    spmm_x<<<N_NODES / 4, 256, 0, stream>>>(adj, deg, Xh, dis, G, sv);
    gemm1_v5<<<N_NODES / 16, 256, 0, stream>>>(G, W1, b1, sv, H);
    gemm2_v5<<<N_NODES / 16, 256, 0, stream>>>(H, W2, b2, dis, M2ph);
    wpool_a<<<dim3(N_GRAPHS, 4), 128, 0, stream>>>(u, M2ph, part);
    wpool_b<<<N_GRAPHS, 128, 0, stream>>>(part, batch, out);
}

// Round 8
// 161.355 us; speedup vs baseline: 1.2938x; 1.2938x over previous
//
#include <hip/hip_runtime.h>
#include <hip/hip_bf16.h>

#define N_NODES 8192
#define N_EDGES 262144
#define F_INDIM 128
#define HID 256
#define F_OUT 128
#define N_GRAPHS 64
#define WPR (N_NODES / 32)   // 256 words per bitmask row
#define CAP 160              // max supported degree (Poisson(64), 12 sigma headroom)
#define NQ 32                // wpool j-chunks

struct alignas(8) bf4 { __hip_bfloat16 a, b, c, d; };

__device__ inline float2 bf2unpack(unsigned int u) {
    float2 r;
    r.x = __uint_as_float(u << 16);          // low ushort  -> col 2l
    r.y = __uint_as_float(u & 0xffff0000u);  // high ushort -> col 2l+1
    return r;
}

// ---------------------------------------------------------------------------
// 0. Cast X (f32) -> Xh (bf16), float4 vectorized
// ---------------------------------------------------------------------------
__global__ __launch_bounds__(256) void cast_x(const float* __restrict__ X,
                                              __hip_bfloat16* __restrict__ Xh) {
    int i = blockIdx.x * 256 + threadIdx.x;   // i < N*F/4
    float4 v = ((const float4*)X)[i];
    bf4 o;
    o.a = __float2bfloat16(v.x); o.b = __float2bfloat16(v.y);
    o.c = __float2bfloat16(v.z); o.d = __float2bfloat16(v.w);
    ((bf4*)Xh)[i] = o;
}

// ---------------------------------------------------------------------------
// 1. Edge scatter into symmetric bitmask (dedup by construction)  [R2 proven]
// ---------------------------------------------------------------------------
__global__ __launch_bounds__(256) void scatter_edges(const int* __restrict__ ei,
                                                     unsigned int* __restrict__ mask) {
    int e = blockIdx.x * blockDim.x + threadIdx.x;
    if (e >= N_EDGES) return;
    int s = ei[e];
    int d = ei[N_EDGES + e];
    if ((unsigned)s >= N_NODES || (unsigned)d >= N_NODES) return;  // safety guard
    atomicOr(&mask[(size_t)s * WPR + (d >> 5)], 1u << (d & 31));
    atomicOr(&mask[(size_t)d * WPR + (s >> 5)], 1u << (s & 31));
}

// ---------------------------------------------------------------------------
// 2. Bitmask -> fixed-stride adjacency + deg + dis. One wave/row. [R2 proven]
// ---------------------------------------------------------------------------
__global__ __launch_bounds__(256) void build_adj(const unsigned int* __restrict__ mask,
                                                 int* __restrict__ adj,
                                                 int* __restrict__ deg,
                                                 float* __restrict__ dis) {
    int row = (blockIdx.x * blockDim.x + threadIdx.x) >> 6;
    int lane = threadIdx.x & 63;
    if (row >= N_NODES) return;
    const uint4* r = (const uint4*)(mask + (size_t)row * WPR);
    uint4 v = r[lane];
    int cnt = __popc(v.x) + __popc(v.y) + __popc(v.z) + __popc(v.w);
    int scan = cnt;  // inclusive scan across 64 lanes
    for (int off = 1; off < 64; off <<= 1) {
        int n = __shfl_up(scan, off);
        if (lane >= off) scan += n;
    }
    int tot = __shfl(scan, 63);
    int idx = scan - cnt;  // exclusive prefix = my write base
    int* ap = adj + (size_t)row * CAP;
    int wbase = lane << 7;  // lane*4 words * 32 bits
    unsigned int wd;
    wd = v.x; while (wd) { int b = __ffs(wd) - 1; wd &= wd - 1; if (idx < CAP) ap[idx] = wbase + b;      ++idx; }
    wd = v.y; while (wd) { int b = __ffs(wd) - 1; wd &= wd - 1; if (idx < CAP) ap[idx] = wbase + 32 + b; ++idx; }
    wd = v.z; while (wd) { int b = __ffs(wd) - 1; wd &= wd - 1; if (idx < CAP) ap[idx] = wbase + 64 + b; ++idx; }
    wd = v.w; while (wd) { int b = __ffs(wd) - 1; wd &= wd - 1; if (idx < CAP) ap[idx] = wbase + 96 + b; ++idx; }
    if (lane == 63) { deg[row] = tot; dis[row] = rsqrtf((float)(tot + 1)); }  // +1: identity
}

// ---------------------------------------------------------------------------
// 3. spmm_x_fused: per row i (one wave):
//      G[i][c] = dis_i*(dis_i*X[i][c] + sum_j dis_j*X[j][c])
//      sv[i]   = dis_i*(dis_i + sum_j dis_j)
//      u[i][g] = sum_{j in N(i), batch_j==g} dis_j + [batch_i==g]*dis_i
//    (u transposed [node][graph] for coalesced writes; symmetric adjacency
//     makes the per-i histogram of neighbors exactly build_u's per-j column.)
// ---------------------------------------------------------------------------
__global__ __launch_bounds__(256) void spmm_x_fused(const int* __restrict__ adj,
                                                    const int* __restrict__ deg,
                                                    const __hip_bfloat16* __restrict__ Xh,
                                                    const float* __restrict__ dis,
                                                    const int* __restrict__ batch,
                                                    float* __restrict__ G,
                                                    float* __restrict__ sv,
                                                    float* __restrict__ u) {
    int w = threadIdx.x >> 6, lane = threadIdx.x & 63;
    int i = blockIdx.x * 4 + w;
    __shared__ int nb[4][CAP];
    __shared__ float nbd[4][CAP];
    __shared__ float ul[4][64];
    int d = deg[i]; if (d > CAP) d = CAP;
    const unsigned int* Xu = (const unsigned int*)Xh;  // row stride 64 uints
    ul[w][lane] = 0.0f;
    float p = 0.0f;
    for (int t = lane; t < d; t += 64) {
        int j = adj[(size_t)i * CAP + t];
        float dj = dis[j];
        nb[w][t] = j; nbd[w][t] = dj;
        p += dj;
    }
    __syncthreads();
    // u histogram: neighbors of i, bucketed by their graph
    for (int t = lane; t < d; t += 64)
        atomicAdd(&ul[w][batch[nb[w][t]] & 63], nbd[w][t]);
    for (int off = 32; off; off >>= 1) p += __shfl_down(p, off);
    float di = dis[i];
    if (lane == 0) {
        sv[i] = di * (di + p);
        atomicAdd(&ul[w][batch[i] & 63], di);   // +I diagonal
    }
    float2 xi = bf2unpack(Xu[(size_t)i * 64 + lane]);
    float2 a0 = {di * xi.x, di * xi.y};
    float2 a1 = {0,0}, a2 = {0,0}, a3 = {0,0}, a4 = {0,0}, a5 = {0,0}, a6 = {0,0}, a7 = {0,0};
    int k = 0;
    for (; k + 8 <= d; k += 8) {
#define GATH(Q, ACC) { int j = nb[w][k+Q]; float dj = nbd[w][k+Q]; \
        float2 f = bf2unpack(Xu[(size_t)j * 64 + lane]); \
        ACC.x += dj * f.x; ACC.y += dj * f.y; }
        GATH(0, a0) GATH(1, a1) GATH(2, a2) GATH(3, a3)
        GATH(4, a4) GATH(5, a5) GATH(6, a6) GATH(7, a7)
    }
    for (; k < d; ++k) GATH(0, a0)
#undef GATH
    float2 s;
    s.x = ((a0.x + a1.x) + (a2.x + a3.x)) + ((a4.x + a5.x) + (a6.x + a7.x));
    s.y = ((a0.y + a1.y) + (a2.y + a3.y)) + ((a4.y + a5.y) + (a6.y + a7.y));
    float2 o = {di * s.x, di * s.y};
    ((float2*)(G + (size_t)i * F_INDIM))[lane] = o;
    __syncthreads();   // ul complete (cross-lane via LDS atomics)
    u[(size_t)i * N_GRAPHS + lane] = ul[w][lane];  // coalesced 256B per wave
}

// ---------------------------------------------------------------------------
// 4. fused_gemm: per 16-row block:
//      Htile = relu(G@W1 + sv*b1)   (kept in LDS, never written to HBM)
//      M2ph  = bf16(dis*(Htile@W2 + b2))
// ---------------------------------------------------------------------------
__global__ __launch_bounds__(256) void fused_gemm(const float* __restrict__ G,
                                                  const float* __restrict__ W1,
                                                  const float* __restrict__ b1,
                                                  const float* __restrict__ sv,
                                                  const float* __restrict__ W2,
                                                  const float* __restrict__ b2,
                                                  const float* __restrict__ dis,
                                                  __hip_bfloat16* __restrict__ M2ph) {
    int i0 = blockIdx.x * 16;
    int t = threadIdx.x;
    __shared__ float xs[16][F_INDIM];   // 8 KB
    __shared__ float hs[16][HID];       // 16 KB
    for (int v = t; v < 16 * F_INDIM / 4; v += 256) {
        int r = v >> 5, c4 = (v & 31) << 2;
        *(float4*)&xs[r][c4] = *(const float4*)&G[(size_t)(i0 + r) * F_INDIM + c4];
    }
    __syncthreads();
    // ---- stage 1: 4 rows x 4 cols per thread over K=128 ----
    {
        int tc = t & 63, tr = t >> 6;
        float4 acc0 = {0,0,0,0}, acc1 = {0,0,0,0}, acc2 = {0,0,0,0}, acc3 = {0,0,0,0};
        const float* wp = W1 + 4 * tc;
        for (int k = 0; k < F_INDIM; k += 4) {
            float4 w0 = *(const float4*)&wp[(size_t)(k + 0) * HID];
            float4 w1 = *(const float4*)&wp[(size_t)(k + 1) * HID];
            float4 w2 = *(const float4*)&wp[(size_t)(k + 2) * HID];
            float4 w3 = *(const float4*)&wp[(size_t)(k + 3) * HID];
#define ROW(R, ACC) { \
            float4 g4 = *(const float4*)&xs[4 * tr + R][k]; \
            ACC.x += g4.x*w0.x; ACC.y += g4.x*w0.y; ACC.z += g4.x*w0.z; ACC.w += g4.x*w0.w; \
            ACC.x += g4.y*w1.x; ACC.y += g4.y*w1.y; ACC.z += g4.y*w1.z; ACC.w += g4.y*w1.w; \
            ACC.x += g4.z*w2.x; ACC.y += g4.z*w2.y; ACC.z += g4.z*w2.z; ACC.w += g4.z*w2.w; \
            ACC.x += g4.w*w3.x; ACC.y += g4.w*w3.y; ACC.z += g4.w*w3.z; ACC.w += g4.w*w3.w; }
            ROW(0, acc0) ROW(1, acc1) ROW(2, acc2) ROW(3, acc3)
#undef ROW
        }
        float4 b = *(const float4*)&b1[4 * tc];
#define EPI(R, ACC) { \
            int r = 4 * tr + R; float s = sv[i0 + r]; float4 res = ACC; \
            hs[r][4 * tc + 0] = fmaxf(res.x + s * b.x, 0.f); \
            hs[r][4 * tc + 1] = fmaxf(res.y + s * b.y, 0.f); \
            hs[r][4 * tc + 2] = fmaxf(res.z + s * b.z, 0.f); \
            hs[r][4 * tc + 3] = fmaxf(res.w + s * b.w, 0.f); }
        EPI(0, acc0) EPI(1, acc1) EPI(2, acc2) EPI(3, acc3)
#undef EPI
    }
    __syncthreads();
    // ---- stage 2: 2 rows x 4 cols per thread over K=256 ----
    {
        int tc = t & 31, tr = t >> 5;
        float4 acc0 = {0,0,0,0}, acc1 = {0,0,0,0};
        const float* wp = W2 + 4 * tc;
        for (int k = 0; k < HID; k += 4) {
            float4 w0 = *(const float4*)&wp[(size_t)(k + 0) * F_OUT];
            float4 w1 = *(const float4*)&wp[(size_t)(k + 1) * F_OUT];
            float4 w2 = *(const float4*)&wp[(size_t)(k + 2) * F_OUT];
            float4 w3 = *(const float4*)&wp[(size_t)(k + 3) * F_OUT];
#define ROW(R, ACC) { \
            float4 g4 = *(const float4*)&hs[2 * tr + R][k]; \
            ACC.x += g4.x*w0.x; ACC.y += g4.x*w0.y; ACC.z += g4.x*w0.z; ACC.w += g4.x*w0.w; \
            ACC.x += g4.y*w1.x; ACC.y += g4.y*w1.y; ACC.z += g4.y*w1.z; ACC.w += g4.y*w1.w; \
            ACC.x += g4.z*w2.x; ACC.y += g4.z*w2.y; ACC.z += g4.z*w2.z; ACC.w += g4.z*w2.w; \
            ACC.x += g4.w*w3.x; ACC.y += g4.w*w3.y; ACC.z += g4.w*w3.z; ACC.w += g4.w*w3.w; }
            ROW(0, acc0) ROW(1, acc1)
#undef ROW
        }
        float4 b = *(const float4*)&b2[4 * tc];
#define EPI(R, ACC) { \
            int i = i0 + 2 * tr + R; float dd = dis[i]; float4 res = ACC; \
            bf4 o; o.a = __float2bfloat16(dd * (res.x + b.x)); o.b = __float2bfloat16(dd * (res.y + b.y)); \
            o.c = __float2bfloat16(dd * (res.z + b.z)); o.d = __float2bfloat16(dd * (res.w + b.w)); \
            *(bf4*)(M2ph + (size_t)i * F_OUT + 4 * tc) = o; }
        EPI(0, acc0) EPI(1, acc1)
#undef EPI
    }
}

// ---------------------------------------------------------------------------
// 5. wpool_a: part[g][q][c] = sum_{j in chunk q} u[j][g] * M2ph[j][c]
//    grid (64, 32) = 2048 blocks; one 256-row chunk per block, u staged in LDS
// ---------------------------------------------------------------------------
__global__ __launch_bounds__(128) void wpool_a(const float* __restrict__ u,
                                               const __hip_bfloat16* __restrict__ M2ph,
                                               float* __restrict__ part) {
    int g = blockIdx.x, q = blockIdx.y, c = threadIdx.x;
    int j0 = q * (N_NODES / NQ);
    const unsigned short* Mu = (const unsigned short*)M2ph;
    __shared__ float us[N_NODES / NQ];   // 256
    us[c]       = u[(size_t)(j0 + c) * N_GRAPHS + g];
    us[c + 128] = u[(size_t)(j0 + c + 128) * N_GRAPHS + g];
    __syncthreads();
    float a0 = 0.f, a1 = 0.f, a2 = 0.f, a3 = 0.f, a4 = 0.f, a5 = 0.f, a6 = 0.f, a7 = 0.f;
    for (int jj = 0; jj < N_NODES / NQ; jj += 8) {
#define TERM(Q, ACC) ACC += us[jj + Q] * __uint_as_float((unsigned)Mu[(size_t)(j0 + jj + Q) * F_OUT + c] << 16);
        TERM(0, a0) TERM(1, a1) TERM(2, a2) TERM(3, a3)
        TERM(4, a4) TERM(5, a5) TERM(6, a6) TERM(7, a7)
#undef TERM
    }
    float s = ((a0 + a1) + (a2 + a3)) + ((a4 + a5) + (a6 + a7));
    part[((size_t)g * NQ + q) * F_OUT + c] = s;
}

// ---------------------------------------------------------------------------
// 6. wpool_b: out[g][c] = (sum_q part[g][q][c]) / cnt_g
// ---------------------------------------------------------------------------
__global__ __launch_bounds__(128) void wpool_b(const float* __restrict__ part,
                                               const int* __restrict__ batch,
                                               float* __restrict__ out) {
    int g = blockIdx.x, c = threadIdx.x;
    int lo = 0, hi = N_NODES;
    while (lo < hi) { int m = (lo + hi) >> 1; if (batch[m] < g) lo = m + 1; else hi = m; }
    int start = lo;
    hi = N_NODES;
    while (lo < hi) { int m = (lo + hi) >> 1; if (batch[m] < g + 1) lo = m + 1; else hi = m; }
    int cnt = lo - start;
    float s = 0.0f;
#pragma unroll
    for (int q = 0; q < NQ; ++q) s += part[((size_t)g * NQ + q) * F_OUT + c];
    out[(size_t)g * F_OUT + c] = s / (float)(cnt > 0 ? cnt : 1);
}

// ---------------------------------------------------------------------------
extern "C" void kernel_launch(void* const* d_in, const int* in_sizes, int n_in,
                              void* d_out, int out_size, void* d_ws, size_t ws_size,
                              hipStream_t stream) {
    const float* X  = (const float*)d_in[0];
    const float* W1 = (const float*)d_in[1];
    const float* b1 = (const float*)d_in[2];
    const float* W2 = (const float*)d_in[3];
    const float* b2 = (const float*)d_in[4];
    const int* ei    = (const int*)d_in[5];
    const int* batch = (const int*)d_in[6];
    float* out = (float*)d_out;

    char* ws = (char*)d_ws;
    // [0, 8MB): mask during build; after build_adj dead, reused for
    // u (2MB, transposed [node][graph]), M2ph (2MB), part (1MB).
    unsigned int* mask   = (unsigned int*)(ws);
    float* u             = (float*)(ws);                    // 2 MB (8192x64)
    __hip_bfloat16* M2ph = (__hip_bfloat16*)(ws + 2097152); // 2 MB (8192x128)
    float* part          = (float*)(ws + 4194304);          // 1 MB (64x32x128)
    float* G   = (float*)(ws + 8388608);                    // 4 MB (8192x128 f32)
    __hip_bfloat16* Xh = (__hip_bfloat16*)(ws + 12582912);  // 2 MB (8192x128 bf16)
    int*   adj = (int*)(ws + 25165824);                     // 5.25 MB
    int*   deg = (int*)(ws + 30408704);                     // 32 KB
    float* dis = (float*)(ws + 30441472);                   // 32 KB
    float* sv  = (float*)(ws + 30474240);                   // 32 KB

    cast_x<<<(N_NODES * F_INDIM / 4) / 256, 256, 0, stream>>>(X, Xh);
    hipMemsetAsync(mask, 0, (size_t)N_NODES * WPR * sizeof(unsigned int), stream);
    scatter_edges<<<N_EDGES / 256, 256, 0, stream>>>(ei, mask);
    build_adj<<<N_NODES / 4, 256, 0, stream>>>(mask, adj, deg, dis);
    spmm_x_fused<<<N_NODES / 4, 256, 0, stream>>>(adj, deg, Xh, dis, batch, G, sv, u);
    fused_gemm<<<N_NODES / 16, 256, 0, stream>>>(G, W1, b1, sv, W2, b2, dis, M2ph);
    wpool_a<<<dim3(N_GRAPHS, NQ), 128, 0, stream>>>(u, M2ph, part);
    wpool_b<<<N_GRAPHS, 128, 0, stream>>>(part, batch, out);
}

// Round 10
// 154.403 us; speedup vs baseline: 1.3520x; 1.0450x over previous
//
#include <hip/hip_runtime.h>
#include <hip/hip_bf16.h>

#define N_NODES 8192
#define N_EDGES 262144
#define F_INDIM 128
#define HID 256
#define F_OUT 128
#define N_GRAPHS 64
#define WPR (N_NODES / 32)   // 256 words per bitmask row
#define CAP 160              // max supported degree (Poisson(64), 12 sigma headroom)
#define NQ 32                // wpool j-chunks

struct alignas(8) bf4 { __hip_bfloat16 a, b, c, d; };

__device__ inline float2 bf2unpack(unsigned int u) {
    float2 r;
    r.x = __uint_as_float(u << 16);          // low ushort  -> col 2l
    r.y = __uint_as_float(u & 0xffff0000u);  // high ushort -> col 2l+1
    return r;
}

// ---------------------------------------------------------------------------
// 1. cast X -> bf16 (blocks 0..1023) and zero mask (blocks 1024..3071)
// ---------------------------------------------------------------------------
__global__ __launch_bounds__(256) void cast_zero(const float* __restrict__ X,
                                                 __hip_bfloat16* __restrict__ Xh,
                                                 unsigned int* __restrict__ mask) {
    int b = blockIdx.x, t = threadIdx.x;
    if (b < 1024) {                       // 1024*256 = N*F/4 float4 casts
        int i = b * 256 + t;
        float4 v = ((const float4*)X)[i];
        bf4 o;
        o.a = __float2bfloat16(v.x); o.b = __float2bfloat16(v.y);
        o.c = __float2bfloat16(v.z); o.d = __float2bfloat16(v.w);
        ((bf4*)Xh)[i] = o;
    } else {                              // 2048*256 = 8MB/16B uint4 zeros
        int i = (b - 1024) * 256 + t;
        uint4 z = {0u, 0u, 0u, 0u};
        ((uint4*)mask)[i] = z;
    }
}

// ---------------------------------------------------------------------------
// 2. Edge scatter into symmetric bitmask (dedup by construction)  [R2 proven]
// ---------------------------------------------------------------------------
__global__ __launch_bounds__(256) void scatter_edges(const int* __restrict__ ei,
                                                     unsigned int* __restrict__ mask) {
    int e = blockIdx.x * blockDim.x + threadIdx.x;
    if (e >= N_EDGES) return;
    int s = ei[e];
    int d = ei[N_EDGES + e];
    if ((unsigned)s >= N_NODES || (unsigned)d >= N_NODES) return;  // safety guard
    atomicOr(&mask[(size_t)s * WPR + (d >> 5)], 1u << (d & 31));
    atomicOr(&mask[(size_t)d * WPR + (s >> 5)], 1u << (s & 31));
}

// ---------------------------------------------------------------------------
// 3. compute_dis: wave per row, popcount -> dis = rsqrt(deg+1)
// ---------------------------------------------------------------------------
__global__ __launch_bounds__(256) void compute_dis(const unsigned int* __restrict__ mask,
                                                   float* __restrict__ dis) {
    int row = (blockIdx.x * blockDim.x + threadIdx.x) >> 6;
    int lane = threadIdx.x & 63;
    uint4 v = ((const uint4*)(mask + (size_t)row * WPR))[lane];
    int c = __popc(v.x) + __popc(v.y) + __popc(v.z) + __popc(v.w);
    for (int off = 32; off; off >>= 1) c += __shfl_down(c, off);
    if (lane == 0) dis[row] = rsqrtf((float)(c + 1));  // +1: identity
}

// ---------------------------------------------------------------------------
// 4. spmm_scan: wave per row i. Scans the mask row to an LDS neighbor list
//    (build_adj's proven scan, LDS-emitted), then:
//      G[i][c] = dis_i*(dis_i*X[i][c] + sum_j dis_j*X[j][c])
//      sv[i]   = dis_i*(dis_i + sum_j dis_j)
//      u[i][g] = sum_{j in N(i), batch_j==g} dis_j + [batch_i==g]*dis_i
// ---------------------------------------------------------------------------
__global__ __launch_bounds__(256) void spmm_scan(const unsigned int* __restrict__ mask,
                                                 const __hip_bfloat16* __restrict__ Xh,
                                                 const float* __restrict__ dis,
                                                 const int* __restrict__ batch,
                                                 float* __restrict__ G,
                                                 float* __restrict__ sv,
                                                 float* __restrict__ u) {
    int w = threadIdx.x >> 6, lane = threadIdx.x & 63;
    int i = blockIdx.x * 4 + w;
    __shared__ int nb[4][CAP];
    __shared__ float nbd[4][CAP];
    __shared__ float ul[4][64];
    ul[w][lane] = 0.0f;
    uint4 v = ((const uint4*)(mask + (size_t)i * WPR))[lane];
    int cnt = __popc(v.x) + __popc(v.y) + __popc(v.z) + __popc(v.w);
    int scan = cnt;
    for (int off = 1; off < 64; off <<= 1) {
        int n = __shfl_up(scan, off);
        if (lane >= off) scan += n;
    }
    int tot = __shfl(scan, 63);
    int idx = scan - cnt;              // exclusive prefix = LDS write base
    int wbase = lane << 7;
    unsigned int wd;
    wd = v.x; while (wd) { int b = __ffs(wd) - 1; wd &= wd - 1; if (idx < CAP) nb[w][idx] = wbase + b;      ++idx; }
    wd = v.y; while (wd) { int b = __ffs(wd) - 1; wd &= wd - 1; if (idx < CAP) nb[w][idx] = wbase + 32 + b; ++idx; }
    wd = v.z; while (wd) { int b = __ffs(wd) - 1; wd &= wd - 1; if (idx < CAP) nb[w][idx] = wbase + 64 + b; ++idx; }
    wd = v.w; while (wd) { int b = __ffs(wd) - 1; wd &= wd - 1; if (idx < CAP) nb[w][idx] = wbase + 96 + b; ++idx; }
    int d = tot; if (d > CAP) d = CAP;
    __syncthreads();
    const unsigned int* Xu = (const unsigned int*)Xh;  // row stride 64 uints
    float p = 0.0f;
    for (int t = lane; t < d; t += 64) {
        int j = nb[w][t];
        float dj = dis[j];
        nbd[w][t] = dj;
        p += dj;
        atomicAdd(&ul[w][batch[j] & 63], dj);
    }
    for (int off = 32; off; off >>= 1) p += __shfl_down(p, off);
    float di = dis[i];
    if (lane == 0) {
        sv[i] = di * (di + p);
        atomicAdd(&ul[w][batch[i] & 63], di);   // +I diagonal
    }
    __syncthreads();   // nbd + ul complete
    float2 xi = bf2unpack(Xu[(size_t)i * 64 + lane]);
    float2 a0 = {di * xi.x, di * xi.y};
    float2 a1 = {0,0}, a2 = {0,0}, a3 = {0,0}, a4 = {0,0}, a5 = {0,0}, a6 = {0,0}, a7 = {0,0};
    int k = 0;
    for (; k + 8 <= d; k += 8) {
#define GATH(Q, ACC) { int j = nb[w][k+Q]; float dj = nbd[w][k+Q]; \
        float2 f = bf2unpack(Xu[(size_t)j * 64 + lane]); \
        ACC.x += dj * f.x; ACC.y += dj * f.y; }
        GATH(0, a0) GATH(1, a1) GATH(2, a2) GATH(3, a3)
        GATH(4, a4) GATH(5, a5) GATH(6, a6) GATH(7, a7)
    }
    for (; k < d; ++k) GATH(0, a0)
#undef GATH
    float2 s;
    s.x = ((a0.x + a1.x) + (a2.x + a3.x)) + ((a4.x + a5.x) + (a6.x + a7.x));
    s.y = ((a0.y + a1.y) + (a2.y + a3.y)) + ((a4.y + a5.y) + (a6.y + a7.y));
    float2 o = {di * s.x, di * s.y};
    ((float2*)(G + (size_t)i * F_INDIM))[lane] = o;
    u[(size_t)i * N_GRAPHS + lane] = ul[w][lane];  // coalesced 256B per wave
}

// ---------------------------------------------------------------------------
// 5. fused_gemm  [R8 proven body] + block 0 zeroes `out` for wpool atomics
// ---------------------------------------------------------------------------
__global__ __launch_bounds__(256) void fused_gemm(const float* __restrict__ G,
                                                  const float* __restrict__ W1,
                                                  const float* __restrict__ b1,
                                                  const float* __restrict__ sv,
                                                  const float* __restrict__ W2,
                                                  const float* __restrict__ b2,
                                                  const float* __restrict__ dis,
                                                  __hip_bfloat16* __restrict__ M2ph,
                                                  float* __restrict__ out) {
    int i0 = blockIdx.x * 16;
    int t = threadIdx.x;
    if (blockIdx.x == 0) {   // zero out (64x128 f32 = 2048 float4)
        float4 z = {0,0,0,0};
        for (int v = t; v < N_GRAPHS * F_OUT / 4; v += 256) ((float4*)out)[v] = z;
    }
    __shared__ float xs[16][F_INDIM];   // 8 KB
    __shared__ float hs[16][HID];       // 16 KB
    for (int v = t; v < 16 * F_INDIM / 4; v += 256) {
        int r = v >> 5, c4 = (v & 31) << 2;
        *(float4*)&xs[r][c4] = *(const float4*)&G[(size_t)(i0 + r) * F_INDIM + c4];
    }
    __syncthreads();
    // ---- stage 1: 4 rows x 4 cols per thread over K=128 ----
    {
        int tc = t & 63, tr = t >> 6;
        float4 acc0 = {0,0,0,0}, acc1 = {0,0,0,0}, acc2 = {0,0,0,0}, acc3 = {0,0,0,0};
        const float* wp = W1 + 4 * tc;
        for (int k = 0; k < F_INDIM; k += 4) {
            float4 w0 = *(const float4*)&wp[(size_t)(k + 0) * HID];
            float4 w1 = *(const float4*)&wp[(size_t)(k + 1) * HID];
            float4 w2 = *(const float4*)&wp[(size_t)(k + 2) * HID];
            float4 w3 = *(const float4*)&wp[(size_t)(k + 3) * HID];
#define ROW(R, ACC) { \
            float4 g4 = *(const float4*)&xs[4 * tr + R][k]; \
            ACC.x += g4.x*w0.x; ACC.y += g4.x*w0.y; ACC.z += g4.x*w0.z; ACC.w += g4.x*w0.w; \
            ACC.x += g4.y*w1.x; ACC.y += g4.y*w1.y; ACC.z += g4.y*w1.z; ACC.w += g4.y*w1.w; \
            ACC.x += g4.z*w2.x; ACC.y += g4.z*w2.y; ACC.z += g4.z*w2.z; ACC.w += g4.z*w2.w; \
            ACC.x += g4.w*w3.x; ACC.y += g4.w*w3.y; ACC.z += g4.w*w3.z; ACC.w += g4.w*w3.w; }
            ROW(0, acc0) ROW(1, acc1) ROW(2, acc2) ROW(3, acc3)
#undef ROW
        }
        float4 b = *(const float4*)&b1[4 * tc];
#define EPI(R, ACC) { \
            int r = 4 * tr + R; float s = sv[i0 + r]; float4 res = ACC; \
            hs[r][4 * tc + 0] = fmaxf(res.x + s * b.x, 0.f); \
            hs[r][4 * tc + 1] = fmaxf(res.y + s * b.y, 0.f); \
            hs[r][4 * tc + 2] = fmaxf(res.z + s * b.z, 0.f); \
            hs[r][4 * tc + 3] = fmaxf(res.w + s * b.w, 0.f); }
        EPI(0, acc0) EPI(1, acc1) EPI(2, acc2) EPI(3, acc3)
#undef EPI
    }
    __syncthreads();
    // ---- stage 2: 2 rows x 4 cols per thread over K=256 ----
    {
        int tc = t & 31, tr = t >> 5;
        float4 acc0 = {0,0,0,0}, acc1 = {0,0,0,0};
        const float* wp = W2 + 4 * tc;
        for (int k = 0; k < HID; k += 4) {
            float4 w0 = *(const float4*)&wp[(size_t)(k + 0) * F_OUT];
            float4 w1 = *(const float4*)&wp[(size_t)(k + 1) * F_OUT];
            float4 w2 = *(const float4*)&wp[(size_t)(k + 2) * F_OUT];
            float4 w3 = *(const float4*)&wp[(size_t)(k + 3) * F_OUT];
#define ROW(R, ACC) { \
            float4 g4 = *(const float4*)&hs[2 * tr + R][k]; \
            ACC.x += g4.x*w0.x; ACC.y += g4.x*w0.y; ACC.z += g4.x*w0.z; ACC.w += g4.x*w0.w; \
            ACC.x += g4.y*w1.x; ACC.y += g4.y*w1.y; ACC.z += g4.y*w1.z; ACC.w += g4.y*w1.w; \
            ACC.x += g4.z*w2.x; ACC.y += g4.z*w2.y; ACC.z += g4.z*w2.z; ACC.w += g4.z*w2.w; \
            ACC.x += g4.w*w3.x; ACC.y += g4.w*w3.y; ACC.z += g4.w*w3.z; ACC.w += g4.w*w3.w; }
            ROW(0, acc0) ROW(1, acc1)
#undef ROW
        }
        float4 b = *(const float4*)&b2[4 * tc];
#define EPI(R, ACC) { \
            int i = i0 + 2 * tr + R; float dd = dis[i]; float4 res = ACC; \
            bf4 o; o.a = __float2bfloat16(dd * (res.x + b.x)); o.b = __float2bfloat16(dd * (res.y + b.y)); \
            o.c = __float2bfloat16(dd * (res.z + b.z)); o.d = __float2bfloat16(dd * (res.w + b.w)); \
            *(bf4*)(M2ph + (size_t)i * F_OUT + 4 * tc) = o; }
        EPI(0, acc0) EPI(1, acc1)
#undef EPI
    }
}

// ---------------------------------------------------------------------------
// 6. wpool: out[g][c] += (1/cnt_g) * sum_{j in chunk q} u[j][g] * M2ph[j][c]
// ---------------------------------------------------------------------------
__global__ __launch_bounds__(128) void wpool(const float* __restrict__ u,
                                             const __hip_bfloat16* __restrict__ M2ph,
                                             const int* __restrict__ batch,
                                             float* __restrict__ out) {
    int g = blockIdx.x, q = blockIdx.y, c = threadIdx.x;
    int j0 = q * (N_NODES / NQ);
    const unsigned short* Mu = (const unsigned short*)M2ph;
    __shared__ float us[N_NODES / NQ];   // 256
    us[c]       = u[(size_t)(j0 + c) * N_GRAPHS + g];
    us[c + 128] = u[(size_t)(j0 + c + 128) * N_GRAPHS + g];
    __syncthreads();
    float a0 = 0.f, a1 = 0.f, a2 = 0.f, a3 = 0.f, a4 = 0.f, a5 = 0.f, a6 = 0.f, a7 = 0.f;
    for (int jj = 0; jj < N_NODES / NQ; jj += 8) {
#define TERM(Q, ACC) ACC += us[jj + Q] * __uint_as_float((unsigned)Mu[(size_t)(j0 + jj + Q) * F_OUT + c] << 16);
        TERM(0, a0) TERM(1, a1) TERM(2, a2) TERM(3, a3)
        TERM(4, a4) TERM(5, a5) TERM(6, a6) TERM(7, a7)
#undef TERM
    }
    float s = ((a0 + a1) + (a2 + a3)) + ((a4 + a5) + (a6 + a7));
    // cnt_g via binary search on sorted batch
    int lo = 0, hi = N_NODES;
    while (lo < hi) { int m = (lo + hi) >> 1; if (batch[m] < g) lo = m + 1; else hi = m; }
    int start = lo;
    hi = N_NODES;
    while (lo < hi) { int m = (lo + hi) >> 1; if (batch[m] < g + 1) lo = m + 1; else hi = m; }
    int cnt = lo - start;
    atomicAdd(&out[(size_t)g * F_OUT + c], s / (float)(cnt > 0 ? cnt : 1));
}

// ---------------------------------------------------------------------------
extern "C" void kernel_launch(void* const* d_in, const int* in_sizes, int n_in,
                              void* d_out, int out_size, void* d_ws, size_t ws_size,
                              hipStream_t stream) {
    const float* X  = (const float*)d_in[0];
    const float* W1 = (const float*)d_in[1];
    const float* b1 = (const float*)d_in[2];
    const float* W2 = (const float*)d_in[3];
    const float* b2 = (const float*)d_in[4];
    const int* ei    = (const int*)d_in[5];
    const int* batch = (const int*)d_in[6];
    float* out = (float*)d_out;

    char* ws = (char*)d_ws;
    // [0, 8MB): mask during build. After spmm_scan (last mask reader), the
    // [2MB,4MB) slice is reused for M2ph (written by fused_gemm, stream-
    // ordered after spmm_scan). u does NOT alias mask: it sits after G/Xh.
    unsigned int* mask   = (unsigned int*)(ws);
    __hip_bfloat16* M2ph = (__hip_bfloat16*)(ws + 2097152); // 2 MB (8192x128)
    float* G   = (float*)(ws + 8388608);                    // 4 MB (8192x128 f32)
    __hip_bfloat16* Xh = (__hip_bfloat16*)(ws + 12582912);  // 2 MB (8192x128 bf16)
    float* u   = (float*)(ws + 14680064);                   // 2 MB (8192x64)
    float* dis = (float*)(ws + 30441472);                   // 32 KB
    float* sv  = (float*)(ws + 30474240);                   // 32 KB

    cast_zero<<<3072, 256, 0, stream>>>(X, Xh, mask);
    scatter_edges<<<N_EDGES / 256, 256, 0, stream>>>(ei, mask);
    compute_dis<<<N_NODES / 4, 256, 0, stream>>>(mask, dis);
    spmm_scan<<<N_NODES / 4, 256, 0, stream>>>(mask, Xh, dis, batch, G, sv, u);
    fused_gemm<<<N_NODES / 16, 256, 0, stream>>>(G, W1, b1, sv, W2, b2, dis, M2ph, out);
    wpool<<<dim3(N_GRAPHS, NQ), 128, 0, stream>>>(u, M2ph, batch, out);
}